// Round 16
// baseline (165.587 us; speedup 1.0000x reference)
//
#include <hip/hip_runtime.h>
#include <hip/hip_fp16.h>

namespace {
constexpr int ICH = 8, IH = 128, IW = 128;
constexpr int CPG = 4, PH = 31;
constexpr int ICS = 516;
constexpr float EPS = 1e-5f;
constexpr float MPX = 126.f * 126.f;
constexpr int TOTAL_OUT = 128 * 64 * PH * PH;
constexpr size_t WS_NEED = (size_t)128 * 16 * 8 * 2 * 4;   // per-eighth stats

typedef _Float16 v8h __attribute__((ext_vector_type(8)));
typedef float v4f __attribute__((ext_vector_type(4)));
typedef float v16f __attribute__((ext_vector_type(16)));
typedef unsigned short u16;
typedef unsigned int u32;

__device__ __forceinline__ void gll16(const void* g, void* l) {
  __builtin_amdgcn_global_load_lds((const __attribute__((address_space(1))) void*)g,
                                   (__attribute__((address_space(3))) void*)l, 16, 0, 0);
}

__device__ __forceinline__ u32 pkh(float a, float b) {
  unsigned short lo = __half_as_ushort(__float2half_rn(a));
  unsigned short hi = __half_as_ushort(__float2half_rn(b));
  return (u32)lo | ((u32)hi << 16);
}

// ---------- main: implicit-GEMM conv via mfma_f32_32x32x16_f16 ----------
// Block = (n, eighth e), 8 waves x 512 thr. Wave = (oc-half h = w>>2, px-tile
// ptile = w&3 covering px 32*ptile..+31). K = tap*8+ic, 5 chunks of K=16
// (chunk kc = taps {2kc, 2kc+1}; tap 9 = pad).
// A: lane row = oc = 32h + (l&31), k = 8*(l>>5)+i  -> af[kc][i] = flip(oc)*W.
// B: lane col = px, k likewise -> one ds_read_b128 per chunk, shared K layout.
// C/D: col(px) = l&31, row(oc_local) = (reg&3)+8*(reg>>2)+4*(l>>5) [m74/m101].
__global__ __launch_bounds__(512, 4) void conv_mfma(
    const float* __restrict__ x, const float* __restrict__ cw,
    const float* __restrict__ cb, const float* __restrict__ gnw,
    const float* __restrict__ sc, float* __restrict__ out,
    float* __restrict__ wsp) {
  __shared__ __align__(16) u16 ring[12][1056];   // 12 rows x 132 px x 8 ic
  __shared__ float red[16][4][2];                // group x px-tile x {S1,S2}

  const int bid = blockIdx.x;
  const int n = bid >> 3, e = bid & 7;
  const int out_lo = e * 16;
  const int out_hi = (e == 7) ? 125 : out_lo + 15;
  const int NST = (e == 7) ? 4 : 5;              // e=7 stages rows 112..127 exactly
  const int t = threadIdx.x;
  const int w = t >> 6, l = t & 63;
  const int ptile = w & 3, h = w >> 2;
  const int hi5 = l >> 5;
  const int pxl = 32 * ptile + (l & 31);

  // Zero the per-row pixel pad (px 128..131): edge-tap lanes read it.
  for (int idx = t; idx < 12 * 32; idx += 512)
    ring[idx >> 5][1024 + (idx & 31)] = 0;

  // A fragments, flip(oc) folded in; taps 9 zero-padded.
  const int ocA = 32 * h + (l & 31);
  const float flipA = (gnw[ocA] * sc[ocA] >= 0.f) ? 1.f : -1.f;
  v8h af[5];
#pragma unroll
  for (int kc = 0; kc < 5; ++kc) {
    const int tap = 2 * kc + hi5;
#pragma unroll
    for (int i = 0; i < 8; ++i)
      af[kc][i] = (tap < 9) ? (_Float16)(flipA * cw[ocA * 72 + i * 9 + tap])
                            : (_Float16)0.f;
  }
  // B per-lane address constants; pad chunk reads offset 0 (broadcast, A=0).
  int eofc[5], dhl[5];
#pragma unroll
  for (int kc = 0; kc < 5; ++kc) {
    const int tap = 2 * kc + hi5;
    if (tap <= 8) {
      dhl[kc] = tap / 3;
      eofc[kc] = (pxl + tap % 3) * 8;
    } else {
      dhl[kc] = 0;
      eofc[kc] = 0;
    }
  }
  // Flip sign bits for this lane's 16 accumulator regs (for un-flip at output).
  u32 fb = 0;
#pragma unroll
  for (int reg = 0; reg < 16; ++reg) {
    const int oc = 32 * h + (reg & 3) + 8 * (reg >> 2) + 4 * hi5;
    if (gnw[oc] * sc[oc] < 0.f) fb |= (1u << reg);
  }
  const float mv = (pxl < 126) ? 1.f : 0.f;      // px 126,127 invalid for stats
  const u16* rb = &ring[0][0];

  // ---- fused staging: thread t stages pixel (t&127) of row (t>>7) ----
  const int srow = t >> 7;                        // 0..3 within stage
  const int spx = t & 127;
  const float* xb = x + (size_t)n * ICH * IH * IW + spx;
  float fs[8];
  auto load_regs = [&](int s) {
    const int grow = out_lo + 4 * s + srow;
    const float* gp = xb + (size_t)grow * IW;
#pragma unroll
    for (int ic = 0; ic < 8; ++ic) fs[ic] = gp[(size_t)ic * (IH * IW)];
  };
  auto write_lds = [&](int s) {
    const int grow = out_lo + 4 * s + srow;
    const int slot = grow % 12;
    uint4 v;
    v.x = pkh(fs[0], fs[1]); v.y = pkh(fs[2], fs[3]);
    v.z = pkh(fs[4], fs[5]); v.w = pkh(fs[6], fs[7]);
    *reinterpret_cast<uint4*>(&ring[slot][spx * 8]) = v;
  };

  load_regs(0);
  write_lds(0);

  float s1[16], pacc[16], s2[4] = {0.f, 0.f, 0.f, 0.f};
#pragma unroll
  for (int reg = 0; reg < 16; ++reg) { s1[reg] = 0.f; pacc[reg] = -3.4e38f; }

  for (int s = 0; s < NST; ++s) {
    __syncthreads();                      // stage s writes visible to all waves
    if (s + 1 < NST) load_regs(s + 1);    // loads fly under the MFMA phase
#pragma unroll
    for (int ri = 0; ri < 4; ++ri) {
      const int r = out_lo + 4 * s - 2 + ri;
      if (r < out_lo || r > out_hi) continue;
      const int rm = r % 12;
      int eoff[5];
#pragma unroll
      for (int kc = 0; kc < 5; ++kc) {
        int sl = rm + dhl[kc];
        if (sl >= 12) sl -= 12;
        eoff[kc] = sl * 1056 + eofc[kc];
      }
      v16f acc = {0.f, 0.f, 0.f, 0.f, 0.f, 0.f, 0.f, 0.f,
                  0.f, 0.f, 0.f, 0.f, 0.f, 0.f, 0.f, 0.f};
#pragma unroll
      for (int kc = 0; kc < 5; ++kc) {
        v8h bf = *reinterpret_cast<const v8h*>(rb + eoff[kc]);
        acc = __builtin_amdgcn_mfma_f32_32x32x16_f16(af[kc], bf, acc, 0, 0, 0);
      }
#pragma unroll
      for (int reg = 0; reg < 16; ++reg) {
        const float v = acc[reg];          // flip(oc)*conv (no bias)
        const float am = mv * v;
        s1[reg] += am;
        s2[reg >> 2] = fmaf(am, am, s2[reg >> 2]);
        pacc[reg] = fmaxf(pacc[reg], v);   // lanes px>=124: window 31 unwritten
      }
      if ((r & 3) == 3) {                  // flush pool window row pr = r>>2
        const int pr = r >> 2;
        const int pc = 8 * ptile + ((l & 31) >> 2);
        const bool writer = ((l & 3) == 0) && (pc < 31);
#pragma unroll
        for (int reg = 0; reg < 16; ++reg) {
          float pm = pacc[reg];
          pm = fmaxf(pm, __shfl_xor(pm, 1, 64));
          pm = fmaxf(pm, __shfl_xor(pm, 2, 64));
          if (writer) {
            const int oc = 32 * h + (reg & 3) + 8 * (reg >> 2) + 4 * hi5;
            const u32 sm = (fb << (31 - reg)) & 0x80000000u;   // un-flip sign
            out[(((size_t)n * 64 + oc) * PH + pr) * PH + pc] =
                __uint_as_float(__float_as_uint(pm) ^ sm);
          }
          pacc[reg] = -3.4e38f;
        }
      }
    }
    // ds_write stage s+1 (rows 4s+4..4s+7): disjoint from stage-s reads.
    if (s + 1 < NST) write_lds(s + 1);
  }

  // ---- stats: reduce over 32 px lanes, un-flip, fold bias per-wave count ----
#pragma unroll
  for (int off = 1; off <= 16; off <<= 1) {
#pragma unroll
    for (int reg = 0; reg < 16; ++reg) s1[reg] += __shfl_xor(s1[reg], off, 64);
#pragma unroll
    for (int j = 0; j < 4; ++j) s2[j] += __shfl_xor(s2[j], off, 64);
  }
  if ((l & 31) == 0) {
    const float rows_e = (float)(out_hi - out_lo + 1);
    const float cnt_w = (ptile == 3 ? 30.f : 32.f) * rows_e;  // wave's px count
#pragma unroll
    for (int j = 0; j < 4; ++j) {
      float S1 = 0.f, S2 = s2[j];
#pragma unroll
      for (int q = 0; q < 4; ++q) {
        const int reg = 4 * j + q;
        const int oc = 32 * h + q + 8 * j + 4 * hi5;
        const float su = (fb & (1u << reg)) ? -s1[reg] : s1[reg];
        const float b = cb[oc];
        S1 += su + cnt_w * b;
        S2 += 2.f * b * su + cnt_w * b * b;
      }
      const int g = 8 * h + 2 * j + hi5;
      red[g][ptile][0] = S1;
      red[g][ptile][1] = S2;
    }
  }
  __syncthreads();
  if (t < 16) {
    const float S1 = red[t][0][0] + red[t][1][0] + red[t][2][0] + red[t][3][0];
    const float S2 = red[t][0][1] + red[t][1][1] + red[t][2][1] + red[t][3][1];
    float* wp = wsp + ((size_t)(n * 16 + t) * 8 + e) * 2;
    wp[0] = S1; wp[1] = S2;
  }
}

// ---------- epilogue kernel: GN affine + clamp over raw pool extremes ----------
__global__ __launch_bounds__(256) void gn_affine_clamp(
    float* __restrict__ out, const float* __restrict__ wsp,
    const float* __restrict__ gnw, const float* __restrict__ gnb,
    const float* __restrict__ sc, const float* __restrict__ cb) {
  int i = blockIdx.x * 256 + threadIdx.x;
  const int stride = gridDim.x * 256;
  for (; i < TOTAL_OUT; i += stride) {
    int c = (i / 961) & 63;
    int n = i / 61504;
    const float* wp = wsp + ((size_t)(n * 16 + (c >> 2)) * 8) * 2;
    float S1 = 0.f, S2 = 0.f;
#pragma unroll
    for (int e = 0; e < 8; ++e) { S1 += wp[2 * e]; S2 += wp[2 * e + 1]; }
    constexpr float invN = 1.f / (4.f * MPX);
    float mean = S1 * invN;
    float var = S2 * invN - mean * mean;
    float inv = rsqrtf(var + EPS);
    float gw = gnw[c];
    float A = gw * inv * sc[c];
    float B = (gnb[c] - mean * inv * gw) * sc[c] + A * cb[c];
    float v = fmaf(A, out[i], B);
    out[i] = fminf(fmaxf(v, 0.f), 1.f);
  }
}

// ---------- f32 fallback (verbatim R6 winner, used only if ws too small) ----------
#define FIN(T, DOSTATS, RE)                                                    \
  {                                                                            \
    float f0 = T[0] + __shfl_xor(T[0], 32, 64);                                \
    float f1 = T[1] + __shfl_xor(T[1], 32, 64);                                \
    float f2 = T[2] + __shfl_xor(T[2], 32, 64);                                \
    float f3 = T[3] + __shfl_xor(T[3], 32, 64);                                \
    if (DOSTATS) {                                                             \
      s1 += f0 + f1 + m23 * (f2 + f3);                                         \
      float qa = fmaf(f0, f0, f1 * f1);                                        \
      float qb = fmaf(f2, f2, f3 * f3);                                        \
      s2 += qa + m23 * qb;                                                     \
    }                                                                          \
    RE = fmaxf(fmaxf(flip * f0, flip * f1), fmaxf(flip * f2, flip * f3));      \
  }
#define ZERO(T) { T[0] = 0.f; T[1] = 0.f; T[2] = 0.f; T[3] = 0.f; }
#define ROWF(RR, T2, T1, T0)                                                   \
  {                                                                            \
    _Pragma("unroll") for (int i4 = 0; i4 < 4; ++i4) {                         \
      const float* rp = bp + (4 * p + i4) * ICS + (RR) * IW + 4 * j;           \
      float4 v4 = *reinterpret_cast<const float4*>(rp);                        \
      float2 v2 = *reinterpret_cast<const float2*>(rp + 4);                    \
      float in[6] = {v4.x, v4.y, v4.z, v4.w, v2.x, v2.y};                      \
      _Pragma("unroll") for (int dw = 0; dw < 3; ++dw) {                       \
        const float w0 = wf[i4 * 9 + dw];                                      \
        const float w1 = wf[i4 * 9 + 3 + dw];                                  \
        const float w2 = wf[i4 * 9 + 6 + dw];                                  \
        _Pragma("unroll") for (int q = 0; q < 4; ++q) {                        \
          T2[q] = fmaf(in[q + dw], w2, T2[q]);                                 \
          T1[q] = fmaf(in[q + dw], w1, T1[q]);                                 \
          T0[q] = fmaf(in[q + dw], w0, T0[q]);                                 \
        }                                                                      \
      }                                                                        \
    }                                                                          \
  }
#define STAGEF(S, X, Y, Z, DOS01, DOWIN)                                       \
  {                                                                            \
    __syncthreads();                                                           \
    const int cur = (S) & 1;                                                   \
    if ((S) < 31) issue(4 * ((S) + 1), cur ^ 1);                               \
    const float* bp = &buf[cur][0][0];                                         \
    float re0, re1, re2, re3;                                                  \
    ROWF(0, X, Y, Z) FIN(X, DOS01, re0) ZERO(X)                                \
    ROWF(1, Y, Z, X) FIN(Y, DOS01, re1) ZERO(Y)                                \
    if (DOWIN) {                                                               \
      float wfin = fmaxf(wprev, fmaxf(re0, re1));                              \
      if (p == 0 && j < 31) mm[c][(S) - 1][j] = __float2half(flip * wfin);     \
    }                                                                          \
    ROWF(2, Z, X, Y) FIN(Z, true, re2) ZERO(Z)                                 \
    ROWF(3, X, Y, Z) FIN(X, true, re3) ZERO(X)                                 \
    wprev = fmaxf(re2, re3);                                                   \
  }

__global__ __launch_bounds__(256, 2) void fused_conv_gn_pool_f32(
    const float* __restrict__ x, const float* __restrict__ cw,
    const float* __restrict__ cb, const float* __restrict__ gnw,
    const float* __restrict__ gnb, const float* __restrict__ sc,
    float* __restrict__ out) {
  __shared__ float buf[2][ICH][ICS];
  __shared__ __half mm[CPG][PH][PH];
  __shared__ float red[8];
  __shared__ float stats[2];

  const int bid = blockIdx.x;
  const int xcd = bid & 7;
  const int kb = bid >> 3;
  const int n = xcd * 16 + (kb >> 4);
  const int g = kb & 15;
  const int t = threadIdx.x;
  const int c = t >> 6;
  const int u = t & 63;
  const int p = u >> 5;
  const int j = u & 31;
  const int gc = g * CPG + c;

  float wf[36];
  {
    const float4* wp = reinterpret_cast<const float4*>(cw + gc * 72 + p * 36);
#pragma unroll
    for (int q = 0; q < 9; ++q) {
      float4 v = wp[q];
      wf[4 * q + 0] = v.x; wf[4 * q + 1] = v.y;
      wf[4 * q + 2] = v.z; wf[4 * q + 3] = v.w;
    }
  }
  const float flip = ((gnw[gc] * sc[gc]) >= 0.f) ? 1.f : -1.f;
  const float m23 = (j < 31) ? 1.f : 0.f;

  const float* xn = x + (size_t)n * ICH * IH * IW;

  auto issue = [&](int br, int which) {
#pragma unroll
    for (int k = 0; k < 4; ++k) {
      const int m = c * 4 + k;
      const int ic = m >> 1;
      const int r2 = (m & 1) * 2;
      const float* gp = xn + (size_t)(ic * IH + br + r2) * IW + u * 4;
      gll16(gp, &buf[which][ic][r2 * IW]);
    }
  };

  issue(0, 0);

  float s1 = 0.f, s2 = 0.f, wprev = 0.f;
  float A0[4] = {0, 0, 0, 0}, A1[4] = {0, 0, 0, 0}, A2[4] = {0, 0, 0, 0};

  STAGEF(0, A0, A1, A2, false, false)
  for (int s = 1; s <= 28; s += 3) {
    STAGEF(s,     A1, A2, A0, true, true)
    STAGEF(s + 1, A2, A0, A1, true, true)
    STAGEF(s + 2, A0, A1, A2, true, true)
  }
  STAGEF(31, A1, A2, A0, true, true)

#pragma unroll
  for (int off = 32; off > 0; off >>= 1) {
    s1 += __shfl_down(s1, off, 64);
    s2 += __shfl_down(s2, off, 64);
  }
  const float bc = cb[gc];
  if (u == 0) {
    float t1 = 0.5f * s1, t2 = 0.5f * s2;
    red[c * 2] = t1 + MPX * bc;
    red[c * 2 + 1] = t2 + 2.f * bc * t1 + MPX * bc * bc;
  }
  __syncthreads();
  if (t == 0) {
    float S1 = red[0] + red[2] + red[4] + red[6];
    float S2 = red[1] + red[3] + red[5] + red[7];
    constexpr float invN = 1.f / (CPG * 126.f * 126.f);
    float mean = S1 * invN;
    float var = S2 * invN - mean * mean;
    stats[0] = mean;
    stats[1] = rsqrtf(var + EPS);
  }
  __syncthreads();
  const float mean = stats[0], inv = stats[1];

  float* outp = out + ((size_t)n * 64 + g * CPG) * (PH * PH);
  for (int kk = 0; kk < 16; ++kk) {
    int idx = t + kk * 256;
    if (idx < CPG * PH * PH) {
      int cc = idx / (PH * PH);
      int rem = idx - cc * (PH * PH);
      float e = __half2float(mm[cc][rem / PH][rem % PH]);
      int gcc = g * CPG + cc;
      float gw = gnw[gcc];
      float A = gw * inv * sc[gcc];
      float B = (gnb[gcc] - mean * inv * gw) * sc[gcc] + A * cb[gcc];
      float v = fmaf(A, e, B);
      v = fminf(fmaxf(v, 0.f), 1.f);
      outp[cc * (PH * PH) + rem] = v;
    }
  }
}
}  // namespace

extern "C" void kernel_launch(void* const* d_in, const int* in_sizes, int n_in,
                              void* d_out, int out_size, void* d_ws, size_t ws_size,
                              hipStream_t stream) {
  const float* x   = (const float*)d_in[0];
  const float* cw  = (const float*)d_in[1];
  const float* cb  = (const float*)d_in[2];
  const float* gnw = (const float*)d_in[3];
  const float* gnb = (const float*)d_in[4];
  const float* sc  = (const float*)d_in[5];
  float* out = (float*)d_out;

  if (ws_size >= WS_NEED) {
    float* wsp = (float*)d_ws;
    hipLaunchKernelGGL(conv_mfma, dim3(1024), dim3(512), 0, stream,
                       x, cw, cb, gnw, sc, out, wsp);
    hipLaunchKernelGGL(gn_affine_clamp, dim3(2048), dim3(256), 0, stream,
                       out, wsp, gnw, gnb, sc, cb);
  } else {
    hipLaunchKernelGGL(fused_conv_gn_pool_f32, dim3(2048), dim3(256), 0, stream,
                       x, cw, cb, gnw, gnb, sc, out);
  }
}

// Round 17
// 143.084 us; speedup vs baseline: 1.1573x; 1.1573x over previous
//
#include <hip/hip_runtime.h>
#include <hip/hip_fp16.h>

namespace {
constexpr int ICH = 8, IH = 128, IW = 128;
constexpr int CPG = 4, PH = 31;
constexpr int ICS = 516;
constexpr float EPS = 1e-5f;
constexpr float MPX = 126.f * 126.f;
constexpr int TOTAL_OUT = 128 * 64 * PH * PH;
constexpr size_t WS_NEED = (size_t)128 * 16 * 8 * 2 * 4;   // per-eighth stats

typedef _Float16 v8h __attribute__((ext_vector_type(8)));
typedef float v4f __attribute__((ext_vector_type(4)));
typedef float v16f __attribute__((ext_vector_type(16)));
typedef unsigned short u16;
typedef unsigned int u32;

__device__ __forceinline__ void gll16(const void* g, void* l) {
  __builtin_amdgcn_global_load_lds((const __attribute__((address_space(1))) void*)g,
                                   (__attribute__((address_space(3))) void*)l, 16, 0, 0);
}

__device__ __forceinline__ u32 pkh(float a, float b) {
  unsigned short lo = __half_as_ushort(__float2half_rn(a));
  unsigned short hi = __half_as_ushort(__float2half_rn(b));
  return (u32)lo | ((u32)hi << 16);
}

// ---------- main: implicit-GEMM conv via mfma_f32_32x32x16_f16 ----------
// Block = (n, eighth e), 8 waves x 512 thr. Wave = (oc-half h = w>>2, px-tile
// ptile = w&3 covering px 32*ptile..+31). K = tap*8+ic, 5 chunks of K=16
// (chunk kc = taps {2kc, 2kc+1}; tap 9 = pad).
// A: lane row = oc = 32h + (l&31), k = 8*(l>>5)+i  -> af[kc][i] = flip(oc)*W.
// B: lane col = px, k likewise -> one ds_read_b128 per chunk, shared K layout.
// C/D: col(px) = l&31, row(oc_local) = (reg&3)+8*(reg>>2)+4*(l>>5) [m74/m101].
// launch_bounds min-waves=2: VGPR budget 256, demand ~100 -> NO SPILL
// (min-waves>=4 pinned 64-reg tier and spilled ~100MB in R2/R3/R5/R16).
__global__ __launch_bounds__(512, 2) void conv_mfma(
    const float* __restrict__ x, const float* __restrict__ cw,
    const float* __restrict__ cb, const float* __restrict__ gnw,
    const float* __restrict__ sc, float* __restrict__ out,
    float* __restrict__ wsp) {
  __shared__ __align__(16) u16 ring[12][1056];   // 12 rows x 132 px x 8 ic
  __shared__ float red[16][4][2];                // group x px-tile x {S1,S2}

  const int bid = blockIdx.x;
  const int n = bid >> 3, e = bid & 7;
  const int out_lo = e * 16;
  const int out_hi = (e == 7) ? 125 : out_lo + 15;
  const int NST = (e == 7) ? 4 : 5;              // e=7 stages rows 112..127 exactly
  const int t = threadIdx.x;
  const int w = t >> 6, l = t & 63;
  const int ptile = w & 3, h = w >> 2;
  const int hi5 = l >> 5;
  const int pxl = 32 * ptile + (l & 31);

  // Zero the per-row pixel pad (px 128..131): edge-tap lanes read it.
  for (int idx = t; idx < 12 * 32; idx += 512)
    ring[idx >> 5][1024 + (idx & 31)] = 0;

  // A fragments, flip(oc) folded in; taps 9 zero-padded.
  const int ocA = 32 * h + (l & 31);
  const float flipA = (gnw[ocA] * sc[ocA] >= 0.f) ? 1.f : -1.f;
  v8h af[5];
#pragma unroll
  for (int kc = 0; kc < 5; ++kc) {
    const int tap = 2 * kc + hi5;
#pragma unroll
    for (int i = 0; i < 8; ++i)
      af[kc][i] = (tap < 9) ? (_Float16)(flipA * cw[ocA * 72 + i * 9 + tap])
                            : (_Float16)0.f;
  }
  // B per-lane address constants; pad chunk reads offset 0 (broadcast, A=0).
  int eofc[5], dhl[5];
#pragma unroll
  for (int kc = 0; kc < 5; ++kc) {
    const int tap = 2 * kc + hi5;
    if (tap <= 8) {
      dhl[kc] = tap / 3;
      eofc[kc] = (pxl + tap % 3) * 8;
    } else {
      dhl[kc] = 0;
      eofc[kc] = 0;
    }
  }
  // Flip sign bits for this lane's 16 accumulator regs (for un-flip at output).
  u32 fb = 0;
#pragma unroll
  for (int reg = 0; reg < 16; ++reg) {
    const int oc = 32 * h + (reg & 3) + 8 * (reg >> 2) + 4 * hi5;
    if (gnw[oc] * sc[oc] < 0.f) fb |= (1u << reg);
  }
  const float mv = (pxl < 126) ? 1.f : 0.f;      // px 126,127 invalid for stats
  const u16* rb = &ring[0][0];

  // ---- fused staging: thread t stages pixel (t&127) of row (t>>7) ----
  const int srow = t >> 7;                        // 0..3 within stage
  const int spx = t & 127;
  const float* xb = x + (size_t)n * ICH * IH * IW + spx;
  float fs[8];
  auto load_regs = [&](int s) {
    const int grow = out_lo + 4 * s + srow;
    const float* gp = xb + (size_t)grow * IW;
#pragma unroll
    for (int ic = 0; ic < 8; ++ic) fs[ic] = gp[(size_t)ic * (IH * IW)];
  };
  auto write_lds = [&](int s) {
    const int grow = out_lo + 4 * s + srow;
    const int slot = grow % 12;
    uint4 v;
    v.x = pkh(fs[0], fs[1]); v.y = pkh(fs[2], fs[3]);
    v.z = pkh(fs[4], fs[5]); v.w = pkh(fs[6], fs[7]);
    *reinterpret_cast<uint4*>(&ring[slot][spx * 8]) = v;
  };

  load_regs(0);
  write_lds(0);

  float s1[16], pacc[16], s2[4] = {0.f, 0.f, 0.f, 0.f};
#pragma unroll
  for (int reg = 0; reg < 16; ++reg) { s1[reg] = 0.f; pacc[reg] = -3.4e38f; }

  for (int s = 0; s < NST; ++s) {
    __syncthreads();                      // stage s writes visible to all waves
    if (s + 1 < NST) load_regs(s + 1);    // loads fly under the MFMA phase
#pragma unroll
    for (int ri = 0; ri < 4; ++ri) {
      const int r = out_lo + 4 * s - 2 + ri;
      if (r < out_lo || r > out_hi) continue;
      const int rm = r % 12;
      int eoff[5];
#pragma unroll
      for (int kc = 0; kc < 5; ++kc) {
        int sl = rm + dhl[kc];
        if (sl >= 12) sl -= 12;
        eoff[kc] = sl * 1056 + eofc[kc];
      }
      v16f acc = {0.f, 0.f, 0.f, 0.f, 0.f, 0.f, 0.f, 0.f,
                  0.f, 0.f, 0.f, 0.f, 0.f, 0.f, 0.f, 0.f};
#pragma unroll
      for (int kc = 0; kc < 5; ++kc) {
        v8h bf = *reinterpret_cast<const v8h*>(rb + eoff[kc]);
        acc = __builtin_amdgcn_mfma_f32_32x32x16_f16(af[kc], bf, acc, 0, 0, 0);
      }
#pragma unroll
      for (int reg = 0; reg < 16; ++reg) {
        const float v = acc[reg];          // flip(oc)*conv (no bias)
        const float am = mv * v;
        s1[reg] += am;
        s2[reg >> 2] = fmaf(am, am, s2[reg >> 2]);
        pacc[reg] = fmaxf(pacc[reg], v);   // lanes px>=124: window 31 unwritten
      }
      if ((r & 3) == 3) {                  // flush pool window row pr = r>>2
        const int pr = r >> 2;
        const int pc = 8 * ptile + ((l & 31) >> 2);
        const bool writer = ((l & 3) == 0) && (pc < 31);
#pragma unroll
        for (int reg = 0; reg < 16; ++reg) {
          float pm = pacc[reg];
          pm = fmaxf(pm, __shfl_xor(pm, 1, 64));
          pm = fmaxf(pm, __shfl_xor(pm, 2, 64));
          if (writer) {
            const int oc = 32 * h + (reg & 3) + 8 * (reg >> 2) + 4 * hi5;
            const u32 sm = (fb << (31 - reg)) & 0x80000000u;   // un-flip sign
            out[(((size_t)n * 64 + oc) * PH + pr) * PH + pc] =
                __uint_as_float(__float_as_uint(pm) ^ sm);
          }
          pacc[reg] = -3.4e38f;
        }
      }
    }
    // ds_write stage s+1 (rows 4s+4..4s+7): disjoint from stage-s reads.
    if (s + 1 < NST) write_lds(s + 1);
  }

  // ---- stats: reduce over 32 px lanes, un-flip, fold bias per-wave count ----
#pragma unroll
  for (int off = 1; off <= 16; off <<= 1) {
#pragma unroll
    for (int reg = 0; reg < 16; ++reg) s1[reg] += __shfl_xor(s1[reg], off, 64);
#pragma unroll
    for (int j = 0; j < 4; ++j) s2[j] += __shfl_xor(s2[j], off, 64);
  }
  if ((l & 31) == 0) {
    const float rows_e = (float)(out_hi - out_lo + 1);
    const float cnt_w = (ptile == 3 ? 30.f : 32.f) * rows_e;  // wave's px count
#pragma unroll
    for (int j = 0; j < 4; ++j) {
      float S1 = 0.f, S2 = s2[j];
#pragma unroll
      for (int q = 0; q < 4; ++q) {
        const int reg = 4 * j + q;
        const int oc = 32 * h + q + 8 * j + 4 * hi5;
        const float su = (fb & (1u << reg)) ? -s1[reg] : s1[reg];
        const float b = cb[oc];
        S1 += su + cnt_w * b;
        S2 += 2.f * b * su + cnt_w * b * b;
      }
      const int g = 8 * h + 2 * j + hi5;
      red[g][ptile][0] = S1;
      red[g][ptile][1] = S2;
    }
  }
  __syncthreads();
  if (t < 16) {
    const float S1 = red[t][0][0] + red[t][1][0] + red[t][2][0] + red[t][3][0];
    const float S2 = red[t][0][1] + red[t][1][1] + red[t][2][1] + red[t][3][1];
    float* wp = wsp + ((size_t)(n * 16 + t) * 8 + e) * 2;
    wp[0] = S1; wp[1] = S2;
  }
}

// ---------- epilogue kernel: GN affine + clamp over raw pool extremes ----------
__global__ __launch_bounds__(256) void gn_affine_clamp(
    float* __restrict__ out, const float* __restrict__ wsp,
    const float* __restrict__ gnw, const float* __restrict__ gnb,
    const float* __restrict__ sc, const float* __restrict__ cb) {
  int i = blockIdx.x * 256 + threadIdx.x;
  const int stride = gridDim.x * 256;
  for (; i < TOTAL_OUT; i += stride) {
    int c = (i / 961) & 63;
    int n = i / 61504;
    const float* wp = wsp + ((size_t)(n * 16 + (c >> 2)) * 8) * 2;
    float S1 = 0.f, S2 = 0.f;
#pragma unroll
    for (int e = 0; e < 8; ++e) { S1 += wp[2 * e]; S2 += wp[2 * e + 1]; }
    constexpr float invN = 1.f / (4.f * MPX);
    float mean = S1 * invN;
    float var = S2 * invN - mean * mean;
    float inv = rsqrtf(var + EPS);
    float gw = gnw[c];
    float A = gw * inv * sc[c];
    float B = (gnb[c] - mean * inv * gw) * sc[c] + A * cb[c];
    float v = fmaf(A, out[i], B);
    out[i] = fminf(fmaxf(v, 0.f), 1.f);
  }
}

// ---------- f32 fallback (verbatim R6 winner, used only if ws too small) ----------
#define FIN(T, DOSTATS, RE)                                                    \
  {                                                                            \
    float f0 = T[0] + __shfl_xor(T[0], 32, 64);                                \
    float f1 = T[1] + __shfl_xor(T[1], 32, 64);                                \
    float f2 = T[2] + __shfl_xor(T[2], 32, 64);                                \
    float f3 = T[3] + __shfl_xor(T[3], 32, 64);                                \
    if (DOSTATS) {                                                             \
      s1 += f0 + f1 + m23 * (f2 + f3);                                         \
      float qa = fmaf(f0, f0, f1 * f1);                                        \
      float qb = fmaf(f2, f2, f3 * f3);                                        \
      s2 += qa + m23 * qb;                                                     \
    }                                                                          \
    RE = fmaxf(fmaxf(flip * f0, flip * f1), fmaxf(flip * f2, flip * f3));      \
  }
#define ZERO(T) { T[0] = 0.f; T[1] = 0.f; T[2] = 0.f; T[3] = 0.f; }
#define ROWF(RR, T2, T1, T0)                                                   \
  {                                                                            \
    _Pragma("unroll") for (int i4 = 0; i4 < 4; ++i4) {                         \
      const float* rp = bp + (4 * p + i4) * ICS + (RR) * IW + 4 * j;           \
      float4 v4 = *reinterpret_cast<const float4*>(rp);                        \
      float2 v2 = *reinterpret_cast<const float2*>(rp + 4);                    \
      float in[6] = {v4.x, v4.y, v4.z, v4.w, v2.x, v2.y};                      \
      _Pragma("unroll") for (int dw = 0; dw < 3; ++dw) {                       \
        const float w0 = wf[i4 * 9 + dw];                                      \
        const float w1 = wf[i4 * 9 + 3 + dw];                                  \
        const float w2 = wf[i4 * 9 + 6 + dw];                                  \
        _Pragma("unroll") for (int q = 0; q < 4; ++q) {                        \
          T2[q] = fmaf(in[q + dw], w2, T2[q]);                                 \
          T1[q] = fmaf(in[q + dw], w1, T1[q]);                                 \
          T0[q] = fmaf(in[q + dw], w0, T0[q]);                                 \
        }                                                                      \
      }                                                                        \
    }                                                                          \
  }
#define STAGEF(S, X, Y, Z, DOS01, DOWIN)                                       \
  {                                                                            \
    __syncthreads();                                                           \
    const int cur = (S) & 1;                                                   \
    if ((S) < 31) issue(4 * ((S) + 1), cur ^ 1);                               \
    const float* bp = &buf[cur][0][0];                                         \
    float re0, re1, re2, re3;                                                  \
    ROWF(0, X, Y, Z) FIN(X, DOS01, re0) ZERO(X)                                \
    ROWF(1, Y, Z, X) FIN(Y, DOS01, re1) ZERO(Y)                                \
    if (DOWIN) {                                                               \
      float wfin = fmaxf(wprev, fmaxf(re0, re1));                              \
      if (p == 0 && j < 31) mm[c][(S) - 1][j] = __float2half(flip * wfin);     \
    }                                                                          \
    ROWF(2, Z, X, Y) FIN(Z, true, re2) ZERO(Z)                                 \
    ROWF(3, X, Y, Z) FIN(X, true, re3) ZERO(X)                                 \
    wprev = fmaxf(re2, re3);                                                   \
  }

__global__ __launch_bounds__(256, 2) void fused_conv_gn_pool_f32(
    const float* __restrict__ x, const float* __restrict__ cw,
    const float* __restrict__ cb, const float* __restrict__ gnw,
    const float* __restrict__ gnb, const float* __restrict__ sc,
    float* __restrict__ out) {
  __shared__ float buf[2][ICH][ICS];
  __shared__ __half mm[CPG][PH][PH];
  __shared__ float red[8];
  __shared__ float stats[2];

  const int bid = blockIdx.x;
  const int xcd = bid & 7;
  const int kb = bid >> 3;
  const int n = xcd * 16 + (kb >> 4);
  const int g = kb & 15;
  const int t = threadIdx.x;
  const int c = t >> 6;
  const int u = t & 63;
  const int p = u >> 5;
  const int j = u & 31;
  const int gc = g * CPG + c;

  float wf[36];
  {
    const float4* wp = reinterpret_cast<const float4*>(cw + gc * 72 + p * 36);
#pragma unroll
    for (int q = 0; q < 9; ++q) {
      float4 v = wp[q];
      wf[4 * q + 0] = v.x; wf[4 * q + 1] = v.y;
      wf[4 * q + 2] = v.z; wf[4 * q + 3] = v.w;
    }
  }
  const float flip = ((gnw[gc] * sc[gc]) >= 0.f) ? 1.f : -1.f;
  const float m23 = (j < 31) ? 1.f : 0.f;

  const float* xn = x + (size_t)n * ICH * IH * IW;

  auto issue = [&](int br, int which) {
#pragma unroll
    for (int k = 0; k < 4; ++k) {
      const int m = c * 4 + k;
      const int ic = m >> 1;
      const int r2 = (m & 1) * 2;
      const float* gp = xn + (size_t)(ic * IH + br + r2) * IW + u * 4;
      gll16(gp, &buf[which][ic][r2 * IW]);
    }
  };

  issue(0, 0);

  float s1 = 0.f, s2 = 0.f, wprev = 0.f;
  float A0[4] = {0, 0, 0, 0}, A1[4] = {0, 0, 0, 0}, A2[4] = {0, 0, 0, 0};

  STAGEF(0, A0, A1, A2, false, false)
  for (int s = 1; s <= 28; s += 3) {
    STAGEF(s,     A1, A2, A0, true, true)
    STAGEF(s + 1, A2, A0, A1, true, true)
    STAGEF(s + 2, A0, A1, A2, true, true)
  }
  STAGEF(31, A1, A2, A0, true, true)

#pragma unroll
  for (int off = 32; off > 0; off >>= 1) {
    s1 += __shfl_down(s1, off, 64);
    s2 += __shfl_down(s2, off, 64);
  }
  const float bc = cb[gc];
  if (u == 0) {
    float t1 = 0.5f * s1, t2 = 0.5f * s2;
    red[c * 2] = t1 + MPX * bc;
    red[c * 2 + 1] = t2 + 2.f * bc * t1 + MPX * bc * bc;
  }
  __syncthreads();
  if (t == 0) {
    float S1 = red[0] + red[2] + red[4] + red[6];
    float S2 = red[1] + red[3] + red[5] + red[7];
    constexpr float invN = 1.f / (CPG * 126.f * 126.f);
    float mean = S1 * invN;
    float var = S2 * invN - mean * mean;
    stats[0] = mean;
    stats[1] = rsqrtf(var + EPS);
  }
  __syncthreads();
  const float mean = stats[0], inv = stats[1];

  float* outp = out + ((size_t)n * 64 + g * CPG) * (PH * PH);
  for (int kk = 0; kk < 16; ++kk) {
    int idx = t + kk * 256;
    if (idx < CPG * PH * PH) {
      int cc = idx / (PH * PH);
      int rem = idx - cc * (PH * PH);
      float e = __half2float(mm[cc][rem / PH][rem % PH]);
      int gcc = g * CPG + cc;
      float gw = gnw[gcc];
      float A = gw * inv * sc[gcc];
      float B = (gnb[gcc] - mean * inv * gw) * sc[gcc] + A * cb[gcc];
      float v = fmaf(A, e, B);
      v = fminf(fmaxf(v, 0.f), 1.f);
      outp[cc * (PH * PH) + rem] = v;
    }
  }
}
}  // namespace

extern "C" void kernel_launch(void* const* d_in, const int* in_sizes, int n_in,
                              void* d_out, int out_size, void* d_ws, size_t ws_size,
                              hipStream_t stream) {
  const float* x   = (const float*)d_in[0];
  const float* cw  = (const float*)d_in[1];
  const float* cb  = (const float*)d_in[2];
  const float* gnw = (const float*)d_in[3];
  const float* gnb = (const float*)d_in[4];
  const float* sc  = (const float*)d_in[5];
  float* out = (float*)d_out;

  if (ws_size >= WS_NEED) {
    float* wsp = (float*)d_ws;
    hipLaunchKernelGGL(conv_mfma, dim3(1024), dim3(512), 0, stream,
                       x, cw, cb, gnw, sc, out, wsp);
    hipLaunchKernelGGL(gn_affine_clamp, dim3(2048), dim3(256), 0, stream,
                       out, wsp, gnw, gnb, sc, cb);
  } else {
    hipLaunchKernelGGL(fused_conv_gn_pool_f32, dim3(2048), dim3(256), 0, stream,
                       x, cw, cb, gnw, gnb, sc, out);
  }
}